// Round 11
// baseline (239.200 us; speedup 1.0000x reference)
//
#include <hip/hip_runtime.h>
#include <stdint.h>

#define B_ 2
#define T_ 2048
#define C_ 1024
#define H_ 16
#define D_ 64
#define M_ (B_*T_)   // 4096

typedef __attribute__((ext_vector_type(8))) short bf16x8;   // 8 bf16 in 4 VGPRs
typedef __attribute__((ext_vector_type(4))) short bf16x4;   // 4 bf16 in 2 VGPRs
typedef __attribute__((ext_vector_type(4))) float f32x4;
typedef unsigned short u16;

#define MFMA32(a, b, c) __builtin_amdgcn_mfma_f32_16x16x32_bf16((a), (b), (c), 0, 0, 0)

__device__ __forceinline__ u16 f2bf(float f) {
  union { float f; uint32_t u; } v; v.f = f;
  uint32_t u = v.u;
  return (u16)((u + 0x7fffu + ((u >> 16) & 1u)) >> 16);   // RNE
}
__device__ __forceinline__ float bf2f_lo(uint32_t u) {   // low bf16 -> f32
  union { uint32_t u; float f; } v; v.u = u << 16; return v.f;
}
__device__ __forceinline__ float bf2f_hi(uint32_t u) {   // high bf16 -> f32
  union { uint32_t u; float f; } v; v.u = u & 0xffff0000u; return v.f;
}

// v_exp_f32 (2^x) without touching libm headers (__exp2f collides with glibc macros)
__device__ __forceinline__ float exp2_fast(float x) { return __builtin_amdgcn_exp2f(x); }

typedef const __attribute__((address_space(1))) void* gas_t;
typedef __attribute__((address_space(3))) void* las_t;
__device__ __forceinline__ void gld_lds16(const void* g, void* l) {
  __builtin_amdgcn_global_load_lds((gas_t)g, (las_t)l, 16, 0, 0);
}

// ---------------- fp32 -> bf16 convert: x + all 4 weights in ONE launch ----------------
__global__ void cvt_all(const float* __restrict__ x,
                        const float* __restrict__ w0, const float* __restrict__ w1,
                        const float* __restrict__ w2, const float* __restrict__ w3,
                        u16* __restrict__ xb,
                        u16* __restrict__ d0, u16* __restrict__ d1,
                        u16* __restrict__ d2, u16* __restrict__ d3) {
  size_t i = ((size_t)blockIdx.x * 256 + threadIdx.x) * 4;
  const float* s; u16* d; size_t off;
  const size_t NX = (size_t)M_ * C_;        // 4M
  const size_t NW = (size_t)C_ * C_;        // 1M
  if (i < NX) { s = x; d = xb; off = i; }
  else {
    size_t j = i - NX;
    int w = (int)(j / NW); off = j - (size_t)w * NW;
    switch (w) {
      case 0: s = w0; d = d0; break;
      case 1: s = w1; d = d1; break;
      case 2: s = w2; d = d2; break;
      default: s = w3; d = d3; break;
    }
  }
  float4 v = *(const float4*)(s + off);
  ushort4 o;
  o.x = f2bf(v.x); o.y = f2bf(v.y); o.z = f2bf(v.z); o.w = f2bf(v.w);
  *(ushort4*)(d + off) = o;
}

// ---------------- GEMM core: C[128x128] = A[M,K] * W[N,K]^T (bf16) ----------------
__device__ __forceinline__ void gemm_core(const u16* __restrict__ A,
                                          const u16* __restrict__ W,
                                          int m0, int n0, int Kt,
                                          f32x4 acc[4][4])
{
  __shared__ u16 As[128*64];
  __shared__ u16 Bs[128*64];
  const int t = threadIdx.x;
  const int lane = t & 63;
  const int wave = t >> 6;
  const int q = lane >> 4;
  const int l15 = lane & 15;
  const int wm = (wave >> 1) * 64;
  const int wn = (wave & 1) * 64;

  #pragma unroll
  for (int i = 0; i < 4; ++i)
    #pragma unroll
    for (int j = 0; j < 4; ++j)
      acc[i][j] = (f32x4){0.f, 0.f, 0.f, 0.f};

  for (int k0 = 0; k0 < Kt; k0 += 64) {
    #pragma unroll
    for (int r = 0; r < 4; ++r) {
      int Lc = r * 256 + t;
      int row = Lc >> 3;
      int gcc = (Lc & 7) ^ (row & 7);
      gld_lds16(A + (size_t)(m0 + row) * Kt + k0 + gcc * 8, As + Lc * 8);
    }
    #pragma unroll
    for (int r = 0; r < 4; ++r) {
      int Lc = r * 256 + t;
      int row = Lc >> 3;
      int gcc = (Lc & 7) ^ (row & 7);
      gld_lds16(W + (size_t)(n0 + row) * Kt + k0 + gcc * 8, Bs + Lc * 8);
    }
    __syncthreads();

    #pragma unroll
    for (int kk = 0; kk < 2; ++kk) {
      bf16x8 af[4], bfr[4];
      #pragma unroll
      for (int i = 0; i < 4; ++i) {
        int m = wm + i * 16 + l15;
        int ch = (kk * 4 + q) ^ (m & 7);
        af[i] = *(const bf16x8*)(As + m * 64 + ch * 8);
      }
      #pragma unroll
      for (int j = 0; j < 4; ++j) {
        int n = wn + j * 16 + l15;
        int ch = (kk * 4 + q) ^ (n & 7);
        bfr[j] = *(const bf16x8*)(Bs + n * 64 + ch * 8);
      }
      #pragma unroll
      for (int i = 0; i < 4; ++i)
        #pragma unroll
        for (int j = 0; j < 4; ++j)
          acc[i][j] = MFMA32(af[i], bfr[j], acc[i][j]);
    }
    __syncthreads();
  }
}

// ---------------- fused QKV projection ----------------
// Q pre-scaled by (1/sqrt(D)) * log2(e) so attention can use exp2 directly.
// Q/K segments run TRANSPOSED (A = weight, B = X) -> coalesced ushort4 stores.
// V stored transposed [b,h][d][pos] with pos = key-permutation within each
// 32-token block: pos = (k&~31)|((k&12)<<1)|((k&16)>>2)|(k&3)  (see attn).
#define QSCALE 0.1803368801111244f
__global__ __launch_bounds__(256, 3)
void gemm_qkv(const u16* __restrict__ X,
              const u16* __restrict__ Wq, const u16* __restrict__ Wk,
              const u16* __restrict__ Wv,
              u16* __restrict__ Q, u16* __restrict__ K, u16* __restrict__ Vt)
{
  const int bm = blockIdx.x;          // token-block 0..31
  const int bn = blockIdx.y;          // 0..23
  const int seg = bn >> 3;            // 0=Q 1=K 2=V
  const int nb = (bn & 7) * 128;      // output-dim block

  const int t = threadIdx.x, lane = t & 63, wave = t >> 6;
  const int q = lane >> 4, l15 = lane & 15;
  const int wm = (wave >> 1) * 64, wn = (wave & 1) * 64;

  f32x4 acc[4][4];

  if (seg < 2) {
    // ---- transposed: C[o][tok] = W[o][k] * X[tok][k] ----
    const u16* W = (seg == 0) ? Wq : Wk;
    gemm_core(W, X, nb, bm * 128, C_, acc);
    u16* dst = (seg == 0) ? Q : K;
    const float scale = (seg == 0) ? QSCALE : 1.0f;
    #pragma unroll
    for (int i = 0; i < 4; ++i) {
      #pragma unroll
      for (int j = 0; j < 4; ++j) {
        const int o = nb + wm + i * 16 + q * 4;      // output-dim base (mod 4 == 0)
        const int h = o >> 6, d = o & 63;
        const int mtok = bm * 128 + wn + j * 16 + l15;
        const int b = mtok >> 11, tt = mtok & (T_ - 1);
        ushort4 pk;
        pk.x = f2bf(acc[i][j][0] * scale); pk.y = f2bf(acc[i][j][1] * scale);
        pk.z = f2bf(acc[i][j][2] * scale); pk.w = f2bf(acc[i][j][3] * scale);
        *(ushort4*)(dst + (((size_t)(b * H_ + h)) * T_ + tt) * D_ + d) = pk;
      }
    }
  } else {
    // ---- normal orientation: r-index runs along tokens -> pack along t ----
    gemm_core(X, Wv, bm * 128, nb, C_, acc);
    #pragma unroll
    for (int i = 0; i < 4; ++i) {
      #pragma unroll
      for (int j = 0; j < 4; ++j) {
        const int mbase = bm * 128 + wm + i * 16 + q * 4;
        const int b = mbase >> 11, tt = mbase & (T_ - 1);
        const int n = nb + wn + j * 16 + l15;
        const int h = n >> 6, d = n & 63;
        const int ttp = (tt & ~31) | ((tt & 12) << 1) | ((tt & 16) >> 2);
        size_t idx = (((size_t)(b * H_ + h)) * D_ + d) * T_ + ttp;
        ushort4 pk;
        pk.x = f2bf(acc[i][j][0]); pk.y = f2bf(acc[i][j][1]);
        pk.z = f2bf(acc[i][j][2]); pk.w = f2bf(acc[i][j][3]);
        *(ushort4*)(Vt + idx) = pk;
      }
    }
  }
}

// ---------------- flash attention (causal), paired q-tiles, SPLIT-K halves ----------------
// Linear (no-max) softmax makes O and l pure sums over keys -> split each pair
// {pr, 31-pr}'s 64-key chunks across 2 half-blocks (chunk index parity == half).
// grid (32,32) = 1024 blocks = 4 blocks/CU (LDS 32 KB) for 2x the resident waves
// and half the serial chain. Halves write UNNORMALIZED bf16 partial O into
// separate buffers (no atomics, no init) + per-row fp32 partial l; gemm_out
// merges O0+O1 and normalizes during its B-staging.
__global__ __launch_bounds__(256, 4)
void attn(const u16* __restrict__ Q, const u16* __restrict__ K,
          const u16* __restrict__ Vt,
          u16* __restrict__ O0, u16* __restrict__ O1,
          float* __restrict__ L0, float* __restrict__ L1)
{
  __shared__ u16 Ks[2][64 * 64];
  __shared__ u16 Vs[2][64 * 64];
  const int t = threadIdx.x;
  const int lane = t & 63, wave = t >> 6;
  const int q = lane >> 4, l15 = lane & 15;
  const int pr = blockIdx.x >> 1;            // pair 0..15
  const int hf = blockIdx.x & 1;             // key-split half
  const int bh = blockIdx.y;
  const int qbA = pr * 64;                   // small tile
  const int qbB = (31 - pr) * 64;            // big tile
  const u16* Qp = Q + (size_t)bh * T_ * D_;
  const u16* Kp = K + (size_t)bh * T_ * D_;
  const u16* Vp = Vt + (size_t)bh * D_ * T_;

  const int rowA = qbA + 4 * l15 + wave;     // wave-interleaved rows
  const int rowB = qbB + 4 * l15 + wave;
  const u16* qra = Qp + (size_t)rowA * 64;
  const u16* qrb = Qp + (size_t)rowB * 64;
  const bf16x8 aqA0 = *(const bf16x8*)(qra + q * 8);
  const bf16x8 aqA1 = *(const bf16x8*)(qra + 32 + q * 8);
  const bf16x8 aqB0 = *(const bf16x8*)(qrb + q * 8);
  const bf16x8 aqB1 = *(const bf16x8*)(qrb + 32 + q * 8);

  f32x4 oA[4], oB[4];
  #pragma unroll
  for (int j = 0; j < 4; ++j) {
    oA[j] = (f32x4){0.f, 0.f, 0.f, 0.f};
    oB[j] = (f32x4){0.f, 0.f, 0.f, 0.f};
  }
  float lsA = 0.f, lsB = 0.f;

  auto stage = [&](int kb, int buf) {
    #pragma unroll
    for (int r = 0; r < 2; ++r) {
      int c = r * 256 + t, rw = c >> 3, gcc = (c & 7) ^ (rw & 7);
      gld_lds16(Kp + (size_t)(kb + rw) * 64 + gcc * 8, &Ks[buf][c * 8]);
    }
    #pragma unroll
    for (int r = 0; r < 2; ++r) {
      int c = r * 256 + t, rw = c >> 3, gcc = (c & 7) ^ (rw & 7);
      gld_lds16(Vp + (size_t)rw * T_ + kb + gcc * 8, &Vs[buf][c * 8]);
    }
  };

  const int kb0 = hf * 64;                   // this half's chunks: kb0, kb0+128, ...
  stage(kb0, 0);
  int cur = 0;
  for (int kb = kb0; kb <= qbB; kb += 128, cur ^= 1) {
    __syncthreads();                         // drains cur's loads; guards buf reuse
    if (kb + 128 <= qbB) stage(kb + 128, cur ^ 1);
    const u16* Kc = &Ks[cur][0];
    const u16* Vc = &Vs[cur][0];

    // ---- K A-frags (lane = key, k = d) — shared by both q-tiles ----
    bf16x8 kf0[4], kf1[4];
    #pragma unroll
    for (int j2 = 0; j2 < 4; ++j2) {
      const int rw = j2 * 16 + l15;
      kf0[j2] = *(const bf16x8*)(Kc + rw * 64 + ((q)     ^ (rw & 7)) * 8);
      kf1[j2] = *(const bf16x8*)(Kc + rw * 64 + ((4 + q) ^ (rw & 7)) * 8);
    }
    // ---- V^T A-frags for K=32 PV (16B chunk ch = kk*4+q, permuted keys) ----
    bf16x8 vfrag[4][2];
    #pragma unroll
    for (int j = 0; j < 4; ++j) {
      const int rw = j * 16 + l15;
      #pragma unroll
      for (int kk = 0; kk < 2; ++kk) {
        const int ch = (kk * 4 + q) ^ (rw & 7);
        vfrag[j][kk] = *(const bf16x8*)(Vc + rw * 64 + ch * 8);
      }
    }

    auto tile_compute = [&](const bf16x8 a0, const bf16x8 a1, f32x4* o,
                            float& lsum, int rowg, bool diag) {
      bf16x4 pb[4];
      #pragma unroll
      for (int j2 = 0; j2 < 4; ++j2) {
        f32x4 z = (f32x4){0.f, 0.f, 0.f, 0.f};
        z = MFMA32(kf0[j2], a0, z);          // S^T = K . Q^T
        z = MFMA32(kf1[j2], a1, z);
        if (diag) {
          #pragma unroll
          for (int r = 0; r < 4; ++r) {
            const int key = kb + j2 * 16 + q * 4 + r;
            if (key > rowg) z[r] = -1e30f;
          }
        }
        float p0 = exp2_fast(z[0]), p1 = exp2_fast(z[1]);
        float p2 = exp2_fast(z[2]), p3 = exp2_fast(z[3]);
        lsum += (p0 + p1) + (p2 + p3);
        pb[j2] = (bf16x4){(short)f2bf(p0), (short)f2bf(p1),
                          (short)f2bf(p2), (short)f2bf(p3)};
      }
      #pragma unroll
      for (int kk = 0; kk < 2; ++kk) {
        const bf16x8 pc = __builtin_shufflevector(pb[2 * kk], pb[2 * kk + 1],
                                                  0, 1, 2, 3, 4, 5, 6, 7);
        #pragma unroll
        for (int j = 0; j < 4; ++j)
          o[j] = MFMA32(vfrag[j][kk], pc, o[j]);   // O^T += V^T . P^T
      }
    };

    tile_compute(aqB0, aqB1, oB, lsB, rowB, kb == qbB);
    if (kb <= qbA)
      tile_compute(aqA0, aqA1, oA, lsA, rowA, kb == qbA);
  }

  // ---- epilogue: quad-reduce partial l, write UNNORMALIZED partials ----
  lsA += __shfl_xor(lsA, 16, 64); lsA += __shfl_xor(lsA, 32, 64);
  lsB += __shfl_xor(lsB, 16, 64); lsB += __shfl_xor(lsB, 32, 64);

  u16* Oh = hf ? O1 : O0;
  float* Lh = hf ? L1 : L0;
  if (q == 0) {
    Lh[(size_t)bh * T_ + rowA] = lsA;        // one lane per row
    Lh[(size_t)bh * T_ + rowB] = lsB;
  }
  const int b = bh >> 4, h = bh & 15;
  #pragma unroll
  for (int j = 0; j < 4; ++j) {
    ushort4 pa, pbk;
    pa.x = f2bf(oA[j][0]); pa.y = f2bf(oA[j][1]);
    pa.z = f2bf(oA[j][2]); pa.w = f2bf(oA[j][3]);
    pbk.x = f2bf(oB[j][0]); pbk.y = f2bf(oB[j][1]);
    pbk.z = f2bf(oB[j][2]); pbk.w = f2bf(oB[j][3]);
    *(ushort4*)(Oh + ((size_t)b * T_ + rowA) * C_ + h * 64 + j * 16 + q * 4) = pa;
    *(ushort4*)(Oh + ((size_t)b * T_ + rowB) * C_ + h * 64 + j * 16 + q * 4) = pbk;
  }
}

// ---------------- output projection (transposed) with fused merge+normalize ----------------
// C[o][tok] = Wo[o][k] * Att[tok][k] where Att = (O0+O1) * rcp(l0+l1) is formed
// during B-staging (head = k0>>6 is uniform per K-iter; an 8-elem chunk never
// crosses a head boundary). fp32 out, float4 stores along o.
__global__ __launch_bounds__(256, 2)
void gemm_out(const u16* __restrict__ O0, const u16* __restrict__ O1,
              const float* __restrict__ L0, const float* __restrict__ L1,
              const u16* __restrict__ Wo, float* __restrict__ Out)
{
  __shared__ u16 As[64 * 64];     // Wo rows (64 outputs)
  __shared__ u16 Bs[128 * 64];    // merged+normalized Att rows (128 tokens)
  const int t = threadIdx.x;
  const int lane = t & 63, wave = t >> 6;
  const int q = lane >> 4, l15 = lane & 15;
  const int wm = (wave >> 1) * 32, wn = (wave & 1) * 64;
  const int m0 = blockIdx.x * 64;           // output-dim
  const int n0 = blockIdx.y * 128;          // tokens

  f32x4 acc[2][4];
  #pragma unroll
  for (int i = 0; i < 2; ++i)
    #pragma unroll
    for (int j = 0; j < 4; ++j)
      acc[i][j] = (f32x4){0.f, 0.f, 0.f, 0.f};

  for (int k0 = 0; k0 < C_; k0 += 64) {
    #pragma unroll
    for (int r = 0; r < 2; ++r) {
      int Lc = r * 256 + t, row = Lc >> 3, gcc = (Lc & 7) ^ (row & 7);
      gld_lds16(Wo + (size_t)(m0 + row) * C_ + k0 + gcc * 8, As + Lc * 8);
    }
    // B-staging: merge O0+O1, normalize by rcp(l0+l1), pack bf16, ds_write
    const int head = k0 >> 6;
    #pragma unroll
    for (int r = 0; r < 4; ++r) {
      int Lc = r * 256 + t, row = Lc >> 3, gcc = (Lc & 7) ^ (row & 7);
      const int tok = n0 + row;
      const int bhl = (tok >> 11) * H_ + head;         // (b,head) index
      const int tloc = tok & (T_ - 1);
      const float inv = __builtin_amdgcn_rcpf(
          L0[(size_t)bhl * T_ + tloc] + L1[(size_t)bhl * T_ + tloc]);
      const size_t src = (size_t)tok * C_ + k0 + gcc * 8;
      uint4 a = *(const uint4*)(O0 + src);
      uint4 bb = *(const uint4*)(O1 + src);
      ushort4 w0, w1;
      w0.x = f2bf((bf2f_lo(a.x) + bf2f_lo(bb.x)) * inv);
      w0.y = f2bf((bf2f_hi(a.x) + bf2f_hi(bb.x)) * inv);
      w0.z = f2bf((bf2f_lo(a.y) + bf2f_lo(bb.y)) * inv);
      w0.w = f2bf((bf2f_hi(a.y) + bf2f_hi(bb.y)) * inv);
      w1.x = f2bf((bf2f_lo(a.z) + bf2f_lo(bb.z)) * inv);
      w1.y = f2bf((bf2f_hi(a.z) + bf2f_hi(bb.z)) * inv);
      w1.z = f2bf((bf2f_lo(a.w) + bf2f_lo(bb.w)) * inv);
      w1.w = f2bf((bf2f_hi(a.w) + bf2f_hi(bb.w)) * inv);
      *(ushort4*)(Bs + Lc * 8)     = w0;
      *(ushort4*)(Bs + Lc * 8 + 4) = w1;
    }
    __syncthreads();

    #pragma unroll
    for (int kk = 0; kk < 2; ++kk) {
      bf16x8 af[2], bfr[4];
      #pragma unroll
      for (int i = 0; i < 2; ++i) {
        int m = wm + i * 16 + l15;
        int ch = (kk * 4 + q) ^ (m & 7);
        af[i] = *(const bf16x8*)(As + m * 64 + ch * 8);
      }
      #pragma unroll
      for (int j = 0; j < 4; ++j) {
        int n = wn + j * 16 + l15;
        int ch = (kk * 4 + q) ^ (n & 7);
        bfr[j] = *(const bf16x8*)(Bs + n * 64 + ch * 8);
      }
      #pragma unroll
      for (int i = 0; i < 2; ++i)
        #pragma unroll
        for (int j = 0; j < 4; ++j)
          acc[i][j] = MFMA32(af[i], bfr[j], acc[i][j]);
    }
    __syncthreads();
  }

  #pragma unroll
  for (int i = 0; i < 2; ++i) {
    #pragma unroll
    for (int j = 0; j < 4; ++j) {
      const int o = m0 + wm + i * 16 + q * 4;        // mod 4 == 0 -> 16B aligned
      const int tok = n0 + wn + j * 16 + l15;
      float4 st = {acc[i][j][0], acc[i][j][1], acc[i][j][2], acc[i][j][3]};
      *(float4*)(Out + (size_t)tok * C_ + o) = st;
    }
  }
}

// ---------------- launcher ----------------
extern "C" void kernel_launch(void* const* d_in, const int* in_sizes, int n_in,
                              void* d_out, int out_size, void* d_ws, size_t ws_size,
                              hipStream_t stream) {
  const float* x  = (const float*)d_in[0];
  const float* wq = (const float*)d_in[1];
  const float* wk = (const float*)d_in[2];
  const float* wv = (const float*)d_in[3];
  const float* wo = (const float*)d_in[4];
  float* out = (float*)d_out;

  u16* ws  = (u16*)d_ws;
  u16* xb  = ws;
  u16* wqb = xb  + (size_t)M_ * C_;
  u16* wkb = wqb + (size_t)C_ * C_;
  u16* wvb = wkb + (size_t)C_ * C_;
  u16* wob = wvb + (size_t)C_ * C_;
  u16* Qb  = wob + (size_t)C_ * C_;    // [B,H,T,D]
  u16* Kb  = Qb  + (size_t)M_ * C_;    // [B,H,T,D]
  u16* Vtb = Kb  + (size_t)M_ * C_;    // [B,H,D,T] key-permuted
  u16* O0b = Vtb + (size_t)M_ * C_;    // [B,T,C] bf16 partial (half 0)
  u16* O1b = O0b + (size_t)M_ * C_;    // [B,T,C] bf16 partial (half 1)
  float* L0b = (float*)(O1b + (size_t)M_ * C_);   // [BH,T] fp32 partial l
  float* L1b = L0b + (size_t)(B_ * H_) * T_;

  cvt_all<<<dim3((M_ * C_ + 4 * C_ * C_) / 1024), 256, 0, stream>>>(
      x, wq, wk, wv, wo, xb, wqb, wkb, wvb, wob);

  gemm_qkv<<<dim3(M_ / 128, 24), 256, 0, stream>>>(xb, wqb, wkb, wvb, Qb, Kb, Vtb);
  attn<<<dim3(32, B_ * H_), 256, 0, stream>>>(Qb, Kb, Vtb, O0b, O1b, L0b, L1b);
  gemm_out<<<dim3(C_ / 64, M_ / 128), 256, 0, stream>>>(O0b, O1b, L0b, L1b, wob, out);
}

// Round 12
// 211.184 us; speedup vs baseline: 1.1327x; 1.1327x over previous
//
#include <hip/hip_runtime.h>
#include <stdint.h>

#define B_ 2
#define T_ 2048
#define C_ 1024
#define H_ 16
#define D_ 64
#define M_ (B_*T_)   // 4096

typedef __attribute__((ext_vector_type(8))) short bf16x8;   // 8 bf16 in 4 VGPRs
typedef __attribute__((ext_vector_type(4))) short bf16x4;   // 4 bf16 in 2 VGPRs
typedef __attribute__((ext_vector_type(4))) float f32x4;
typedef unsigned short u16;

#define MFMA32(a, b, c) __builtin_amdgcn_mfma_f32_16x16x32_bf16((a), (b), (c), 0, 0, 0)

__device__ __forceinline__ u16 f2bf(float f) {
  union { float f; uint32_t u; } v; v.f = f;
  uint32_t u = v.u;
  return (u16)((u + 0x7fffu + ((u >> 16) & 1u)) >> 16);   // RNE
}
__device__ __forceinline__ u16 f2bf_t(float f) {          // truncate (P only)
  union { float f; uint32_t u; } v; v.f = f;
  return (u16)(v.u >> 16);
}
__device__ __forceinline__ float bf2f(u16 u) {
  union { uint32_t u; float f; } v; v.u = (uint32_t)u << 16; return v.f;
}

// v_exp_f32 (2^x) without touching libm headers (__exp2f collides with glibc macros)
__device__ __forceinline__ float exp2_fast(float x) { return __builtin_amdgcn_exp2f(x); }

typedef const __attribute__((address_space(1))) void* gas_t;
typedef __attribute__((address_space(3))) void* las_t;
__device__ __forceinline__ void gld_lds16(const void* g, void* l) {
  __builtin_amdgcn_global_load_lds((gas_t)g, (las_t)l, 16, 0, 0);
}

// ---------------- fp32 -> bf16 convert: x + all 4 weights in ONE launch ----------------
__global__ void cvt_all(const float* __restrict__ x,
                        const float* __restrict__ w0, const float* __restrict__ w1,
                        const float* __restrict__ w2, const float* __restrict__ w3,
                        u16* __restrict__ xb,
                        u16* __restrict__ d0, u16* __restrict__ d1,
                        u16* __restrict__ d2, u16* __restrict__ d3) {
  size_t i = ((size_t)blockIdx.x * 256 + threadIdx.x) * 4;
  const float* s; u16* d; size_t off;
  const size_t NX = (size_t)M_ * C_;        // 4M
  const size_t NW = (size_t)C_ * C_;        // 1M
  if (i < NX) { s = x; d = xb; off = i; }
  else {
    size_t j = i - NX;
    int w = (int)(j / NW); off = j - (size_t)w * NW;
    switch (w) {
      case 0: s = w0; d = d0; break;
      case 1: s = w1; d = d1; break;
      case 2: s = w2; d = d2; break;
      default: s = w3; d = d3; break;
    }
  }
  float4 v = *(const float4*)(s + off);
  ushort4 o;
  o.x = f2bf(v.x); o.y = f2bf(v.y); o.z = f2bf(v.z); o.w = f2bf(v.w);
  *(ushort4*)(d + off) = o;
}

// ---------------- GEMM core: C[128x128] = A[M,K] * W[N,K]^T (bf16) ----------------
__device__ __forceinline__ void gemm_core(const u16* __restrict__ A,
                                          const u16* __restrict__ W,
                                          int m0, int n0, int Kt,
                                          f32x4 acc[4][4])
{
  __shared__ u16 As[128*64];
  __shared__ u16 Bs[128*64];
  const int t = threadIdx.x;
  const int lane = t & 63;
  const int wave = t >> 6;
  const int q = lane >> 4;
  const int l15 = lane & 15;
  const int wm = (wave >> 1) * 64;
  const int wn = (wave & 1) * 64;

  #pragma unroll
  for (int i = 0; i < 4; ++i)
    #pragma unroll
    for (int j = 0; j < 4; ++j)
      acc[i][j] = (f32x4){0.f, 0.f, 0.f, 0.f};

  for (int k0 = 0; k0 < Kt; k0 += 64) {
    #pragma unroll
    for (int r = 0; r < 4; ++r) {
      int Lc = r * 256 + t;
      int row = Lc >> 3;
      int gcc = (Lc & 7) ^ (row & 7);
      gld_lds16(A + (size_t)(m0 + row) * Kt + k0 + gcc * 8, As + Lc * 8);
    }
    #pragma unroll
    for (int r = 0; r < 4; ++r) {
      int Lc = r * 256 + t;
      int row = Lc >> 3;
      int gcc = (Lc & 7) ^ (row & 7);
      gld_lds16(W + (size_t)(n0 + row) * Kt + k0 + gcc * 8, Bs + Lc * 8);
    }
    __syncthreads();

    #pragma unroll
    for (int kk = 0; kk < 2; ++kk) {
      bf16x8 af[4], bfr[4];
      #pragma unroll
      for (int i = 0; i < 4; ++i) {
        int m = wm + i * 16 + l15;
        int ch = (kk * 4 + q) ^ (m & 7);
        af[i] = *(const bf16x8*)(As + m * 64 + ch * 8);
      }
      #pragma unroll
      for (int j = 0; j < 4; ++j) {
        int n = wn + j * 16 + l15;
        int ch = (kk * 4 + q) ^ (n & 7);
        bfr[j] = *(const bf16x8*)(Bs + n * 64 + ch * 8);
      }
      #pragma unroll
      for (int i = 0; i < 4; ++i)
        #pragma unroll
        for (int j = 0; j < 4; ++j)
          acc[i][j] = MFMA32(af[i], bfr[j], acc[i][j]);
    }
    __syncthreads();
  }
}

// ---------------- fused QKV projection ----------------
// Q pre-scaled by (1/sqrt(D)) * log2(e) so attention can use exp2 directly.
// Q/K segments run TRANSPOSED (A = weight, B = X) -> coalesced ushort4 stores.
// V stored transposed [b,h][d][pos] with pos = key-permutation within each
// 32-token block: pos = (k&~31)|((k&12)<<1)|((k&16)>>2)|(k&3)  (see attn).
#define QSCALE 0.1803368801111244f
__global__ __launch_bounds__(256, 3)
void gemm_qkv(const u16* __restrict__ X,
              const u16* __restrict__ Wq, const u16* __restrict__ Wk,
              const u16* __restrict__ Wv,
              u16* __restrict__ Q, u16* __restrict__ K, u16* __restrict__ Vt)
{
  const int bm = blockIdx.x;          // token-block 0..31
  const int bn = blockIdx.y;          // 0..23
  const int seg = bn >> 3;            // 0=Q 1=K 2=V
  const int nb = (bn & 7) * 128;      // output-dim block

  const int t = threadIdx.x, lane = t & 63, wave = t >> 6;
  const int q = lane >> 4, l15 = lane & 15;
  const int wm = (wave >> 1) * 64, wn = (wave & 1) * 64;

  f32x4 acc[4][4];

  if (seg < 2) {
    // ---- transposed: C[o][tok] = W[o][k] * X[tok][k] ----
    const u16* W = (seg == 0) ? Wq : Wk;
    gemm_core(W, X, nb, bm * 128, C_, acc);
    u16* dst = (seg == 0) ? Q : K;
    const float scale = (seg == 0) ? QSCALE : 1.0f;
    #pragma unroll
    for (int i = 0; i < 4; ++i) {
      #pragma unroll
      for (int j = 0; j < 4; ++j) {
        const int o = nb + wm + i * 16 + q * 4;      // output-dim base (mod 4 == 0)
        const int h = o >> 6, d = o & 63;
        const int mtok = bm * 128 + wn + j * 16 + l15;
        const int b = mtok >> 11, tt = mtok & (T_ - 1);
        ushort4 pk;
        pk.x = f2bf(acc[i][j][0] * scale); pk.y = f2bf(acc[i][j][1] * scale);
        pk.z = f2bf(acc[i][j][2] * scale); pk.w = f2bf(acc[i][j][3] * scale);
        *(ushort4*)(dst + (((size_t)(b * H_ + h)) * T_ + tt) * D_ + d) = pk;
      }
    }
  } else {
    // ---- normal orientation: r-index runs along tokens -> pack along t ----
    gemm_core(X, Wv, bm * 128, nb, C_, acc);
    #pragma unroll
    for (int i = 0; i < 4; ++i) {
      #pragma unroll
      for (int j = 0; j < 4; ++j) {
        const int mbase = bm * 128 + wm + i * 16 + q * 4;
        const int b = mbase >> 11, tt = mbase & (T_ - 1);
        const int n = nb + wn + j * 16 + l15;
        const int h = n >> 6, d = n & 63;
        const int ttp = (tt & ~31) | ((tt & 12) << 1) | ((tt & 16) >> 2);
        size_t idx = (((size_t)(b * H_ + h)) * D_ + d) * T_ + ttp;
        ushort4 pk;
        pk.x = f2bf(acc[i][j][0]); pk.y = f2bf(acc[i][j][1]);
        pk.z = f2bf(acc[i][j][2]); pk.w = f2bf(acc[i][j][3]);
        *(ushort4*)(Vt + idx) = pk;
      }
    }
  }
}

// ---------------- flash attention (causal): paired q-tiles + IN-BLOCK split-K ----------------
// 512 threads = 8 waves. Waves 0-3 (half 0) compute 64-key sub-chunk s=0 of each
// staged 128-key chunk; waves 4-7 (half 1) compute s=1. Same total work as the
// 256-thread version but 2x the resident waves and half the serial chain/wave.
// Linear (no-max) softmax => halves merge O (bf16) + l through the retired
// staging LDS at the end; waves 0-3 normalize and store. K/V dbuf 64 KB,
// grid (16,32) = 512 blocks = 2 blocks/CU (LDS 128 of 160 KB).
__global__ __launch_bounds__(512, 4)
void attn(const u16* __restrict__ Q, const u16* __restrict__ K,
          const u16* __restrict__ Vt, u16* __restrict__ Att)
{
  __shared__ u16 Ks[2][128 * 64];   // [key][d], 8 chunks/row, XOR ^(row&7)
  __shared__ u16 Vs[2][64 * 128];   // [d][key], 16 chunks/row, XOR ^(row&15)
  const int t = threadIdx.x;
  const int lane = t & 63, wave = t >> 6;      // wave 0..7
  const int w4 = wave & 3, half = wave >> 2;
  const int q = lane >> 4, l15 = lane & 15;
  const int pr = blockIdx.x;                   // pair 0..15
  const int bh = blockIdx.y;
  const int qbA = pr * 64;                     // small tile
  const int qbB = (31 - pr) * 64;              // big tile
  const u16* Qp = Q + (size_t)bh * T_ * D_;
  const u16* Kp = K + (size_t)bh * T_ * D_;
  const u16* Vp = Vt + (size_t)bh * D_ * T_;

  const int rowA = qbA + 4 * l15 + w4;         // wave-interleaved rows
  const int rowB = qbB + 4 * l15 + w4;
  const u16* qra = Qp + (size_t)rowA * 64;
  const u16* qrb = Qp + (size_t)rowB * 64;
  const bf16x8 aqA0 = *(const bf16x8*)(qra + q * 8);
  const bf16x8 aqA1 = *(const bf16x8*)(qra + 32 + q * 8);
  const bf16x8 aqB0 = *(const bf16x8*)(qrb + q * 8);
  const bf16x8 aqB1 = *(const bf16x8*)(qrb + 32 + q * 8);

  f32x4 oA[4], oB[4];
  #pragma unroll
  for (int j = 0; j < 4; ++j) {
    oA[j] = (f32x4){0.f, 0.f, 0.f, 0.f};
    oB[j] = (f32x4){0.f, 0.f, 0.f, 0.f};
  }
  float lsA = 0.f, lsB = 0.f;

  // stage 128 keys (32 KB) with 512 threads: 2 rounds each for K and V^T
  auto stage = [&](int kb, int buf) {
    #pragma unroll
    for (int r = 0; r < 2; ++r) {
      int c = r * 512 + t, row = c >> 3, gcc = (c & 7) ^ (row & 7);
      gld_lds16(Kp + (size_t)(kb + row) * 64 + gcc * 8, &Ks[buf][c * 8]);
    }
    #pragma unroll
    for (int r = 0; r < 2; ++r) {
      int c = r * 512 + t, row = c >> 4, gcc = (c & 15) ^ (row & 15);
      gld_lds16(Vp + (size_t)row * T_ + kb + gcc * 8, &Vs[buf][c * 8]);
    }
  };

  stage(0, 0);
  int cur = 0;
  for (int kb = 0; kb <= qbB; kb += 128, cur ^= 1) {
    __syncthreads();                           // drains cur's loads; guards buf reuse
    if (kb + 128 <= qbB) stage(kb + 128, cur ^ 1);
    const u16* Kc = &Ks[cur][0];
    const u16* Vc = &Vs[cur][0];

    const int kbase = kb + half * 64;          // this half's sub-chunk
    if (kbase <= qbB) {                        // wave-uniform; no barrier inside
      // ---- K A-frags (lane = key, k = d) — shared by both q-tiles ----
      bf16x8 kf0[4], kf1[4];
      #pragma unroll
      for (int j2 = 0; j2 < 4; ++j2) {
        const int rw = half * 64 + j2 * 16 + l15;
        kf0[j2] = *(const bf16x8*)(Kc + rw * 64 + ((q)     ^ (rw & 7)) * 8);
        kf1[j2] = *(const bf16x8*)(Kc + rw * 64 + ((4 + q) ^ (rw & 7)) * 8);
      }
      // ---- V^T A-frags: chunk (2*half+kk)*4+q of 16/row (permuted keys) ----
      bf16x8 vfrag[4][2];
      #pragma unroll
      for (int j = 0; j < 4; ++j) {
        const int rw = j * 16 + l15;
        #pragma unroll
        for (int kk = 0; kk < 2; ++kk) {
          const int cc = ((2 * half + kk) * 4 + q) ^ (rw & 15);
          vfrag[j][kk] = *(const bf16x8*)(Vc + rw * 128 + cc * 8);
        }
      }

      auto tile_compute = [&](const bf16x8 a0, const bf16x8 a1, f32x4* o,
                              float& lsum, int rowg, bool diag) {
        bf16x4 pb[4];
        #pragma unroll
        for (int j2 = 0; j2 < 4; ++j2) {
          f32x4 z = (f32x4){0.f, 0.f, 0.f, 0.f};
          z = MFMA32(kf0[j2], a0, z);          // S^T = K . Q^T
          z = MFMA32(kf1[j2], a1, z);
          if (diag) {
            #pragma unroll
            for (int r = 0; r < 4; ++r) {
              const int key = kbase + j2 * 16 + q * 4 + r;
              if (key > rowg) z[r] = -1e30f;
            }
          }
          float p0 = exp2_fast(z[0]), p1 = exp2_fast(z[1]);
          float p2 = exp2_fast(z[2]), p3 = exp2_fast(z[3]);
          lsum += (p0 + p1) + (p2 + p3);
          pb[j2] = (bf16x4){(short)f2bf_t(p0), (short)f2bf_t(p1),
                            (short)f2bf_t(p2), (short)f2bf_t(p3)};
        }
        #pragma unroll
        for (int kk = 0; kk < 2; ++kk) {
          const bf16x8 pc = __builtin_shufflevector(pb[2 * kk], pb[2 * kk + 1],
                                                    0, 1, 2, 3, 4, 5, 6, 7);
          #pragma unroll
          for (int j = 0; j < 4; ++j)
            o[j] = MFMA32(vfrag[j][kk], pc, o[j]);   // O^T += V^T . P^T
        }
      };

      tile_compute(aqB0, aqB1, oB, lsB, rowB, kbase == qbB);
      if (kbase <= qbA)
        tile_compute(aqA0, aqA1, oA, lsA, rowA, kbase == qbA);
    }
  }

  // ---- quad-reduce partial l (every lane ends with its row's partial sum) ----
  lsA += __shfl_xor(lsA, 16, 64); lsA += __shfl_xor(lsA, 32, 64);
  lsB += __shfl_xor(lsB, 16, 64); lsB += __shfl_xor(lsB, 32, 64);

  // ---- merge halves through the retired staging LDS ----
  u16* mo = &Ks[0][0];                 // 16 KB: (w4*64+lane)*32 u16 (oA 16, oB 16)
  float* ml = (float*)&Vs[0][0];       // 2 KB:  (w4*64+lane)*2 floats
  __syncthreads();                     // all frag reads of Ks/Vs complete
  if (half == 1) {
    const int base = (w4 * 64 + lane) * 32;
    #pragma unroll
    for (int j = 0; j < 4; ++j) {
      ushort4 pa, pbk;
      pa.x = f2bf(oA[j][0]); pa.y = f2bf(oA[j][1]);
      pa.z = f2bf(oA[j][2]); pa.w = f2bf(oA[j][3]);
      pbk.x = f2bf(oB[j][0]); pbk.y = f2bf(oB[j][1]);
      pbk.z = f2bf(oB[j][2]); pbk.w = f2bf(oB[j][3]);
      *(ushort4*)(mo + base + j * 4)      = pa;
      *(ushort4*)(mo + base + 16 + j * 4) = pbk;
    }
    ml[(w4 * 64 + lane) * 2]     = lsA;
    ml[(w4 * 64 + lane) * 2 + 1] = lsB;
  }
  __syncthreads();
  if (half == 0) {
    const int base = (w4 * 64 + lane) * 32;
    lsA += ml[(w4 * 64 + lane) * 2];
    lsB += ml[(w4 * 64 + lane) * 2 + 1];
    const float invA = __builtin_amdgcn_rcpf(lsA);
    const float invB = __builtin_amdgcn_rcpf(lsB);
    const int b = bh >> 4, h = bh & 15;
    #pragma unroll
    for (int j = 0; j < 4; ++j) {
      ushort4 ma = *(const ushort4*)(mo + base + j * 4);
      ushort4 mb = *(const ushort4*)(mo + base + 16 + j * 4);
      ushort4 pa, pbk;
      pa.x = f2bf((oA[j][0] + bf2f(ma.x)) * invA);
      pa.y = f2bf((oA[j][1] + bf2f(ma.y)) * invA);
      pa.z = f2bf((oA[j][2] + bf2f(ma.z)) * invA);
      pa.w = f2bf((oA[j][3] + bf2f(ma.w)) * invA);
      pbk.x = f2bf((oB[j][0] + bf2f(mb.x)) * invB);
      pbk.y = f2bf((oB[j][1] + bf2f(mb.y)) * invB);
      pbk.z = f2bf((oB[j][2] + bf2f(mb.z)) * invB);
      pbk.w = f2bf((oB[j][3] + bf2f(mb.w)) * invB);
      *(ushort4*)(Att + ((size_t)b * T_ + rowA) * C_ + h * 64 + j * 16 + q * 4) = pa;
      *(ushort4*)(Att + ((size_t)b * T_ + rowB) * C_ + h * 64 + j * 16 + q * 4) = pbk;
    }
  }
}

// ---------------- output projection (transposed): fp32 out, float4 stores ----------------
// C[o][tok] = Wo[o][k] * Att[tok][k]; r-index runs along o -> float4 along n.
__global__ __launch_bounds__(256, 2)
void gemm_out(const u16* __restrict__ Att, const u16* __restrict__ Wo,
              float* __restrict__ Out)
{
  __shared__ u16 As[64 * 64];     // Wo rows (64 outputs)
  __shared__ u16 Bs[128 * 64];    // Att rows (128 tokens)
  const int t = threadIdx.x;
  const int lane = t & 63, wave = t >> 6;
  const int q = lane >> 4, l15 = lane & 15;
  const int wm = (wave >> 1) * 32, wn = (wave & 1) * 64;
  const int m0 = blockIdx.x * 64;           // output-dim
  const int n0 = blockIdx.y * 128;          // tokens

  f32x4 acc[2][4];
  #pragma unroll
  for (int i = 0; i < 2; ++i)
    #pragma unroll
    for (int j = 0; j < 4; ++j)
      acc[i][j] = (f32x4){0.f, 0.f, 0.f, 0.f};

  for (int k0 = 0; k0 < C_; k0 += 64) {
    #pragma unroll
    for (int r = 0; r < 2; ++r) {
      int Lc = r * 256 + t, row = Lc >> 3, gcc = (Lc & 7) ^ (row & 7);
      gld_lds16(Wo + (size_t)(m0 + row) * C_ + k0 + gcc * 8, As + Lc * 8);
    }
    #pragma unroll
    for (int r = 0; r < 4; ++r) {
      int Lc = r * 256 + t, row = Lc >> 3, gcc = (Lc & 7) ^ (row & 7);
      gld_lds16(Att + (size_t)(n0 + row) * C_ + k0 + gcc * 8, Bs + Lc * 8);
    }
    __syncthreads();

    #pragma unroll
    for (int kk = 0; kk < 2; ++kk) {
      bf16x8 af[2], bfr[4];
      #pragma unroll
      for (int i = 0; i < 2; ++i) {
        int m = wm + i * 16 + l15;
        int ch = (kk * 4 + q) ^ (m & 7);
        af[i] = *(const bf16x8*)(As + m * 64 + ch * 8);
      }
      #pragma unroll
      for (int j = 0; j < 4; ++j) {
        int n = wn + j * 16 + l15;
        int ch = (kk * 4 + q) ^ (n & 7);
        bfr[j] = *(const bf16x8*)(Bs + n * 64 + ch * 8);
      }
      #pragma unroll
      for (int i = 0; i < 2; ++i)
        #pragma unroll
        for (int j = 0; j < 4; ++j)
          acc[i][j] = MFMA32(af[i], bfr[j], acc[i][j]);
    }
    __syncthreads();
  }

  #pragma unroll
  for (int i = 0; i < 2; ++i) {
    #pragma unroll
    for (int j = 0; j < 4; ++j) {
      const int o = m0 + wm + i * 16 + q * 4;        // mod 4 == 0 -> 16B aligned
      const int tok = n0 + wn + j * 16 + l15;
      float4 st = {acc[i][j][0], acc[i][j][1], acc[i][j][2], acc[i][j][3]};
      *(float4*)(Out + (size_t)tok * C_ + o) = st;
    }
  }
}

// ---------------- launcher ----------------
extern "C" void kernel_launch(void* const* d_in, const int* in_sizes, int n_in,
                              void* d_out, int out_size, void* d_ws, size_t ws_size,
                              hipStream_t stream) {
  const float* x  = (const float*)d_in[0];
  const float* wq = (const float*)d_in[1];
  const float* wk = (const float*)d_in[2];
  const float* wv = (const float*)d_in[3];
  const float* wo = (const float*)d_in[4];
  float* out = (float*)d_out;

  u16* ws  = (u16*)d_ws;
  u16* xb  = ws;
  u16* wqb = xb  + (size_t)M_ * C_;
  u16* wkb = wqb + (size_t)C_ * C_;
  u16* wvb = wkb + (size_t)C_ * C_;
  u16* wob = wvb + (size_t)C_ * C_;
  u16* Qb  = wob + (size_t)C_ * C_;    // [B,H,T,D]
  u16* Kb  = Qb  + (size_t)M_ * C_;    // [B,H,T,D]
  u16* Vtb = Kb  + (size_t)M_ * C_;    // [B,H,D,T] key-permuted
  u16* Atb = Vtb + (size_t)M_ * C_;    // [B,T,C]

  cvt_all<<<dim3((M_ * C_ + 4 * C_ * C_) / 1024), 256, 0, stream>>>(
      x, wq, wk, wv, wo, xb, wqb, wkb, wvb, wob);

  gemm_qkv<<<dim3(M_ / 128, 24), 256, 0, stream>>>(xb, wqb, wkb, wvb, Qb, Kb, Vtb);
  attn<<<dim3(16, B_ * H_), 512, 0, stream>>>(Qb, Kb, Vtb, Atb);
  gemm_out<<<dim3(C_ / 64, M_ / 128), 256, 0, stream>>>(Atb, wob, out);
}